// Round 6
// baseline (16871.922 us; speedup 1.0000x reference)
//
#include <hip/hip_runtime.h>
#include <stdint.h>

// Problem dims
#define TT 2048
#define BB 32
#define II 256
#define HH 512
#define OO 1024
#define NWGL 64    // WGs per layer (each owns 8 hidden units = 32 gate columns)
#define NWG 128
#define RING 32    // ring slots per layer (32 KB each)
#define SLOTB (BB * HH * 2)  // 32 KB

typedef __attribute__((ext_vector_type(8))) short short8;
typedef __attribute__((ext_vector_type(4))) float floatx4;

__device__ __forceinline__ unsigned short f2bf(float f) {
  union { float f; unsigned u; } v; v.f = f;
  unsigned r = v.u + 0x7FFFu + ((v.u >> 16) & 1u);  // RNE
  return (unsigned short)(r >> 16);
}
__device__ __forceinline__ float bf2f(unsigned short b) {
  union { float f; unsigned u; } v; v.u = ((unsigned)b) << 16; return v.f;
}
__device__ __forceinline__ float sigmf(float x) { return 1.0f / (1.0f + __expf(-x)); }
__device__ __forceinline__ float tanhfast(float x) {
  float xc = fminf(fmaxf(x, -15.f), 15.f);
  float e = __expf(2.f * xc);
  return (e - 1.f) / (e + 1.f);
}

// Coherent (MALL-direct) 16B load via 64-bit VGPR address: d <- [va + IMM].
#define LD1(d, va, IMM)                                                     \
  asm volatile("global_load_dwordx4 %0, %1, off offset:" IMM " sc0 sc1"     \
               : "=v"(d) : "v"(va) : "memory")
// Cached 16B load (normal L1/L2 path) — for read-only x.
#define LD1C(d, va, IMM)                                                    \
  asm volatile("global_load_dwordx4 %0, %1, off offset:" IMM                \
               : "=v"(d) : "v"(va) : "memory")

#define ISSUE8(dst, va) do {                                                \
    LD1(dst[0], va, "0");   LD1(dst[1], va, "64");                          \
    LD1(dst[2], va, "128"); LD1(dst[3], va, "192");                         \
    LD1(dst[4], va, "256"); LD1(dst[5], va, "320");                         \
    LD1(dst[6], va, "384"); LD1(dst[7], va, "448"); } while (0)
#define ISSUE8C(dst, va) do {                                               \
    LD1C(dst[0], va, "0");   LD1C(dst[1], va, "64");                        \
    LD1C(dst[2], va, "128"); LD1C(dst[3], va, "192");                       \
    LD1C(dst[4], va, "256"); LD1C(dst[5], va, "320");                       \
    LD1C(dst[6], va, "384"); LD1C(dst[7], va, "448"); } while (0)

// Wait until <=N vector-mem ops outstanding; fence the scheduler (rule #18).
#define WAITV(N) do {                                                       \
    asm volatile("s_waitcnt vmcnt(" #N ")" ::: "memory");                   \
    __builtin_amdgcn_sched_barrier(0); } while (0)

#define MF8(tt_, src, wbase) do {                                           \
    _Pragma("unroll")                                                       \
    for (int j = 0; j < 8; j++) {                                           \
      acc[0][tt_] = __builtin_amdgcn_mfma_f32_16x16x32_bf16(src[j], wf[0][(wbase) + j], acc[0][tt_], 0, 0, 0); \
      acc[1][tt_] = __builtin_amdgcn_mfma_f32_16x16x32_bf16(src[j], wf[1][(wbase) + j], acc[1][tt_], 0, 0, 0); \
    } } while (0)

// Coherent dword load (seq / progress words).
#define PROGREAD(dst, addr64)                                               \
  asm volatile("global_load_dword %0, %1, off sc0 sc1"                      \
               : "=v"(dst) : "v"(addr64) : "memory")

// Publish seq word for (slot): arr[slot*64 + g] = val (lane 0 only).
#define SEQSTORE(arr, slot, val) do {                                       \
    if (lane == 0) {                                                        \
      unsigned long long _a = (unsigned long long)(arr) +                   \
          (unsigned long long)((slot) * 64 + g) * 4;                        \
      int _v = (val);                                                       \
      asm volatile("global_store_dword %0, %1, off sc0 sc1"                 \
                   :: "v"(_a), "v"(_v) : "memory");                         \
    } } while (0)

// Gate nonlinearities + c/h update + LDS pack + coalesced coherent h store.
#define TAIL(hwaddr) do {                                                   \
  _Pragma("unroll")                                                         \
  for (int tau = 0; tau < 2; tau++) {                                       \
    _Pragma("unroll")                                                       \
    for (int tt = 0; tt < 2; tt++) {                                        \
      _Pragma("unroll")                                                     \
      for (int r = 0; r < 4; r++) {                                         \
        float val = acc[tau][tt][r];                                        \
        float nl = (gate == 2) ? tanhfast(val) : sigmf(val);                \
        int base2 = (lane & 48) | u;                                        \
        float iv = __shfl(nl, base2);                                       \
        float fv = __shfl(nl, base2 | 4);                                   \
        float gv = __shfl(nl, base2 | 8);                                   \
        float ov = __shfl(nl, base2 | 12);                                  \
        if (gate == 0) {                                                    \
          float cn = fv * cst[tau][tt][r] + iv * gv;                        \
          cst[tau][tt][r] = cn;                                             \
          float hn = ov * tanhfast(cn);                                     \
          int b = tt * 16 + krow * 4 + r;                                   \
          sh[b][tau * 4 + u] = f2bf(hn);                                    \
        }                                                                   \
      }                                                                     \
    }                                                                       \
  }                                                                         \
  asm volatile("s_waitcnt lgkmcnt(0)" ::: "memory");                        \
  __builtin_amdgcn_sched_barrier(0);                                        \
  if (lane < 32) {                                                          \
    short8 v = *reinterpret_cast<const short8*>(&sh[lane][0]);              \
    unsigned long long sa = (hwaddr) + stoff;                               \
    asm volatile("global_store_dwordx4 %0, %1, off sc0 sc1"                 \
                 :: "v"(sa), "v"(v) : "memory");                            \
  } } while (0)

// ---------------- x fp32 -> bf16 convert ----------------
__global__ void k_convert_x(const float* __restrict__ x, ushort* __restrict__ xb, int n4) {
  int i = blockIdx.x * blockDim.x + threadIdx.x;
  int stride = gridDim.x * blockDim.x;
  const float4* xf = reinterpret_cast<const float4*>(x);
  ushort4* ob = reinterpret_cast<ushort4*>(xb);
  for (; i < n4; i += stride) {
    float4 f = xf[i];
    ushort4 o;
    o.x = f2bf(f.x); o.y = f2bf(f.y); o.z = f2bf(f.z); o.w = f2bf(f.w);
    ob[i] = o;
  }
}

// ---------------- init: ring slot 31 = initial h, seed seq arrays ----------
// Runs every call (stream-ordered before k_lstm): replay-deterministic, and
// seeds make within-run tags unique -> no ABA across graph replays.
__global__ void k_init(const float* __restrict__ h0in,
                       ushort* __restrict__ h0ring, ushort* __restrict__ h1ring,
                       int* __restrict__ h0seq, int* __restrict__ h1seq,
                       int* __restrict__ pr1) {
  int i = threadIdx.x;
  ushort* s0 = h0ring + (RING - 1) * BB * HH;
  ushort* s1 = h1ring + (RING - 1) * BB * HH;
  for (int k = i; k < BB * HH; k += blockDim.x) {
    s0[k] = f2bf(h0in[k]);
    s1[k] = f2bf(h0in[BB * HH + k]);
  }
  for (int k = i; k < RING * 64; k += blockDim.x) {
    int v = (k >= (RING - 1) * 64) ? -1 : (int)0x80000000;  // slot31 = tag -1
    h0seq[k] = v;
    h1seq[k] = v;
  }
  for (int k = i; k < 64; k += blockDim.x) pr1[k] = -1;
}

// ---------------- persistent recurrence kernel (barrier-free) ----------------
// 128 WGs x 1 wave. Producer->consumer sync is pure dataflow:
//   producer: data stores -> vmcnt(0) drain -> seq[slot][g] = t
//   consumer: load 64 seq words, __all(== expected), retry; THEN issue data
//   loads (issued-after-completion => serviced after seq => data complete).
// No atomics, no barrier tree, no cache-wide ops. Ring depth 32; peer skew
// <=1 by validation; L0 checks L1 consume-progress every 8 phases (slack 24).
__global__ __launch_bounds__(64, 1) void k_lstm(
    const ushort* __restrict__ xb,
    const float* __restrict__ w_ih0, const float* __restrict__ w_hh0,
    const float* __restrict__ b_ih0, const float* __restrict__ b_hh0,
    const float* __restrict__ w_ih1, const float* __restrict__ w_hh1,
    const float* __restrict__ b_ih1, const float* __restrict__ b_hh1,
    const float* __restrict__ c0in,
    ushort* __restrict__ h0ring, ushort* __restrict__ h1ring,
    int* __restrict__ h0seq, int* __restrict__ h1seq,
    int* __restrict__ pr1)
{
  __shared__ ushort sh[BB][8];  // 512B store-coalescing tile
  const int wg = blockIdx.x;
  const int lane = threadIdx.x;
  const bool isL0 = wg < NWGL;
  const int g = isL0 ? wg : wg - NWGL;
  const int col = lane & 15;
  const int krow = lane >> 4;
  const int u = col & 3;
  const int gate = col >> 2;  // 0=i 1=f 2=g 3=o

  // --- pack weight B-fragments into registers (bf16) ---
  short8 wf[2][32];
#define LOADW(dst, base, rowlen, kbase, tau) do {                             \
    const int _grow = gate * HH + g * 8 + (tau) * 4 + u;                      \
    const float* _p = (base) + (size_t)_grow * (rowlen) + (kbase) + krow * 8; \
    short8 _r;                                                                \
    _Pragma("unroll")                                                         \
    for (int _j = 0; _j < 8; _j++) _r[_j] = (short)f2bf(_p[_j]);              \
    (dst) = _r; } while (0)

  if (isL0) {
#pragma unroll
    for (int tau = 0; tau < 2; tau++) {
#pragma unroll
      for (int kk = 0; kk < 8; kk++)  LOADW(wf[tau][kk],      w_ih0, II, kk * 32, tau);
#pragma unroll
      for (int kk = 0; kk < 16; kk++) LOADW(wf[tau][8 + kk],  w_hh0, HH, kk * 32, tau);
    }
  } else {
#pragma unroll
    for (int tau = 0; tau < 2; tau++) {
#pragma unroll
      for (int kk = 0; kk < 16; kk++) LOADW(wf[tau][kk],      w_ih1, HH, kk * 32, tau);
#pragma unroll
      for (int kk = 0; kk < 16; kk++) LOADW(wf[tau][16 + kk], w_hh1, HH, kk * 32, tau);
    }
  }
  float bias[2];
#pragma unroll
  for (int tau = 0; tau < 2; tau++) {
    const int grow = gate * HH + g * 8 + tau * 4 + u;
    bias[tau] = isL0 ? (b_ih0[grow] + b_hh0[grow]) : (b_ih1[grow] + b_hh1[grow]);
  }

  // --- c state in fp32 registers (used in gate==0 lanes) ---
  float cst[2][2][4];
  {
    const float* cbase = c0in + (isL0 ? 0 : 1) * BB * HH;
#pragma unroll
    for (int tau = 0; tau < 2; tau++)
#pragma unroll
      for (int tt = 0; tt < 2; tt++)
#pragma unroll
        for (int r = 0; r < 4; r++) {
          int b = tt * 16 + krow * 4 + r;
          cst[tau][tt][r] = cbase[b * HH + g * 8 + tau * 4 + u];
        }
  }

  const unsigned long long h0rb = (unsigned long long)h0ring;
  const unsigned long long h1rb = (unsigned long long)h1ring;
  const int vo00 = col * 1024 + krow * 16;  // [32][512]bf16 tile; tt=1 = +16384
  const unsigned long long stoff = (unsigned long long)(lane * 1024 + g * 16);

  short8 wa[8], wb[8], wc[8], wd[8];
  floatx4 acc[2][2];
  const floatx4 bi0 = (floatx4){ bias[0], bias[0], bias[0], bias[0] };
  const floatx4 bi1 = (floatx4){ bias[1], bias[1], bias[1], bias[1] };

  if (isL0) {
    // =============== layer 0 loop ===============
    const unsigned long long xbase = (unsigned long long)xb + (col * 512 + krow * 16);
    for (int t = 0; t < TT; ++t) {
      // validate h0[t-1] (slot (t-1)&31, tag t-1)
      {
        const unsigned long long sa = (unsigned long long)h0seq +
            (unsigned long long)(((t + 31) & 31) * 64 + lane) * 4;
        int sv; PROGREAD(sv, sa); WAITV(0);
        while (!__all(sv == t - 1)) {
          __builtin_amdgcn_s_sleep(1); PROGREAD(sv, sa); WAITV(0);
        }
      }
      // anti-overrun guard vs L1 consume progress (every 8 phases, slack 24)
      if (((t & 7) == 0) && t >= 32) {
        const unsigned long long pa = (unsigned long long)pr1 + lane * 4ull;
        int pv; PROGREAD(pv, pa); WAITV(0);
        while (!__all(pv >= t - 24)) {
          __builtin_amdgcn_s_sleep(4); PROGREAD(pv, pa); WAITV(0);
        }
      }
      acc[0][0] = bi0; acc[0][1] = bi0; acc[1][0] = bi1; acc[1][1] = bi1;
      const unsigned long long ha = h0rb + (unsigned long long)((t + 31) & 31) * SLOTB + vo00;
      const unsigned long long xa = xbase + (unsigned long long)t * (BB * II * 2);
      ISSUE8(wa, ha); ISSUE8(wb, ha + 512); ISSUE8(wc, ha + 16384); ISSUE8(wd, ha + 16896);
      WAITV(24); MF8(0, wa, 8);  ISSUE8C(wa, xa);
      WAITV(24); MF8(0, wb, 16); ISSUE8C(wb, xa + 8192);
      WAITV(24); MF8(1, wc, 8);
      WAITV(16); MF8(1, wd, 16);
      WAITV(8);  MF8(0, wa, 0);
      WAITV(0);  MF8(1, wb, 0);
      TAIL(h0rb + (unsigned long long)(t & 31) * SLOTB);
      WAITV(0);                        // drain data stores
      SEQSTORE(h0seq, (t & 31), t);    // publish (ordered after data)
    }
  } else {
    // =============== layer 1 loop ===============
    for (int t = 0; t < TT; ++t) {
      // validate h0[t] (slot t&31, tag t) AND h1[t-1] (slot (t-1)&31, tag t-1)
      {
        const unsigned long long sa0 = (unsigned long long)h0seq +
            (unsigned long long)((t & 31) * 64 + lane) * 4;
        const unsigned long long sa1 = (unsigned long long)h1seq +
            (unsigned long long)(((t + 31) & 31) * 64 + lane) * 4;
        int s0, s1; PROGREAD(s0, sa0); PROGREAD(s1, sa1); WAITV(0);
        while (!(__all(s0 == t) & __all(s1 == t - 1))) {
          __builtin_amdgcn_s_sleep(1);
          PROGREAD(s0, sa0); PROGREAD(s1, sa1); WAITV(0);
        }
      }
      acc[0][0] = bi0; acc[0][1] = bi0; acc[1][0] = bi1; acc[1][1] = bi1;
      const unsigned long long a0 = h0rb + (unsigned long long)(t & 31) * SLOTB + vo00;
      const unsigned long long a1 = h1rb + (unsigned long long)((t + 31) & 31) * SLOTB + vo00;
      ISSUE8(wa, a0); ISSUE8(wb, a0 + 512); ISSUE8(wc, a0 + 16384); ISSUE8(wd, a0 + 16896);
      WAITV(24); MF8(0, wa, 0); ISSUE8(wa, a1);
      WAITV(24); MF8(0, wb, 8); ISSUE8(wb, a1 + 512);
      WAITV(24); MF8(1, wc, 0); ISSUE8(wc, a1 + 16384);
      WAITV(24); MF8(1, wd, 8); ISSUE8(wd, a1 + 16896);
      WAITV(24); MF8(0, wa, 16);
      WAITV(16); MF8(0, wb, 24);
      WAITV(8);  MF8(1, wc, 16);
      WAITV(0);  MF8(1, wd, 24);
      // publish consume progress (all data loads for phase t are complete)
      if (lane == 0) {
        unsigned long long pa = (unsigned long long)pr1 + (unsigned long long)g * 4;
        int pv = t;
        asm volatile("global_store_dword %0, %1, off sc0 sc1"
                     :: "v"(pa), "v"(pv) : "memory");
      }
      TAIL(h1rb + (unsigned long long)(t & 31) * SLOTB);
      WAITV(0);                        // drain data stores (+progress store)
      SEQSTORE(h1seq, (t & 31), t);    // publish
    }
  }
}

// ---------------- FC + log_softmax ----------------
__global__ __launch_bounds__(256) void k_fc(const ushort* __restrict__ h1,
                                            const float* __restrict__ fcw,
                                            const float* __restrict__ fcb,
                                            float* __restrict__ out) {
  __shared__ float hsh[HH];
  __shared__ float red[256];
  const int b = blockIdx.x, tid = threadIdx.x;
  for (int k = tid; k < HH; k += 256) hsh[k] = bf2f(h1[b * HH + k]);
  __syncthreads();
  float lg[4];
#pragma unroll
  for (int q = 0; q < 4; q++) {
    int o = q * 256 + tid;
    float acc = fcb[o];
    const float* wr = fcw + (size_t)o * HH;
#pragma unroll 4
    for (int k = 0; k < HH; k += 4) {
      float4 w4 = *reinterpret_cast<const float4*>(wr + k);
      acc += hsh[k] * w4.x + hsh[k + 1] * w4.y + hsh[k + 2] * w4.z + hsh[k + 3] * w4.w;
    }
    lg[q] = acc;
  }
  float m = fmaxf(fmaxf(lg[0], lg[1]), fmaxf(lg[2], lg[3]));
  red[tid] = m; __syncthreads();
  for (int s = 128; s > 0; s >>= 1) { if (tid < s) red[tid] = fmaxf(red[tid], red[tid + s]); __syncthreads(); }
  m = red[0]; __syncthreads();
  float se = 0.f;
#pragma unroll
  for (int q = 0; q < 4; q++) se += __expf(lg[q] - m);
  red[tid] = se; __syncthreads();
  for (int s = 128; s > 0; s >>= 1) { if (tid < s) red[tid] += red[tid + s]; __syncthreads(); }
  float lse = m + logf(red[0]);
#pragma unroll
  for (int q = 0; q < 4; q++) out[b * OO + q * 256 + tid] = lg[q] - lse;
}

extern "C" void kernel_launch(void* const* d_in, const int* in_sizes, int n_in,
                              void* d_out, int out_size, void* d_ws, size_t ws_size,
                              hipStream_t stream) {
  const float* x     = (const float*)d_in[0];
  const float* h0    = (const float*)d_in[1];
  const float* c0    = (const float*)d_in[2];
  const float* w_ih0 = (const float*)d_in[3];
  const float* w_hh0 = (const float*)d_in[4];
  const float* b_ih0 = (const float*)d_in[5];
  const float* b_hh0 = (const float*)d_in[6];
  const float* w_ih1 = (const float*)d_in[7];
  const float* w_hh1 = (const float*)d_in[8];
  const float* b_ih1 = (const float*)d_in[9];
  const float* b_hh1 = (const float*)d_in[10];
  const float* fcw   = (const float*)d_in[11];
  const float* fcb   = (const float*)d_in[12];
  float* out = (float*)d_out;

  char* ws = (char*)d_ws;
  size_t off = 0;
  ushort* xb     = (ushort*)(ws + off); off += (size_t)TT * BB * II * 2;     // 33.5 MB
  ushort* h0ring = (ushort*)(ws + off); off += (size_t)RING * BB * HH * 2;   // 1 MB
  ushort* h1ring = (ushort*)(ws + off); off += (size_t)RING * BB * HH * 2;   // 1 MB
  int* h0seq = (int*)(ws + off); off += RING * 64 * sizeof(int);
  int* h1seq = (int*)(ws + off); off += RING * 64 * sizeof(int);
  int* pr1   = (int*)(ws + off); off += 64 * sizeof(int);

  k_convert_x<<<2048, 256, 0, stream>>>(x, xb, TT * BB * II / 4);
  k_init<<<1, 256, 0, stream>>>(h0, h0ring, h1ring, h0seq, h1seq, pr1);
  k_lstm<<<NWG, 64, 0, stream>>>(xb, w_ih0, w_hh0, b_ih0, b_hh0,
                                 w_ih1, w_hh1, b_ih1, b_hh1, c0,
                                 h0ring, h1ring, h0seq, h1seq, pr1);
  // h1[2047] lives in ring slot 2047&31 = 31
  k_fc<<<BB, 256, 0, stream>>>(h1ring + (RING - 1) * BB * HH, fcw, fcb, out);
}